// Round 8
// baseline (385.867 us; speedup 1.0000x reference)
//
#include <hip/hip_runtime.h>
#include <hip/hip_fp16.h>

#define SLOTS 64
#define NB 1024  // histogram/scatter blocks

// ---- fp8 e4m3 (OCP) helpers, HW converters on gfx950 ----
__device__ __forceinline__ unsigned char f32_to_fp8(float v) {
  return (unsigned char)(__builtin_amdgcn_cvt_pk_fp8_f32(v, 0.f, 0, false) & 0xff);
}
__device__ __forceinline__ float fp8_to_f32(unsigned char b) {
  return __builtin_amdgcn_cvt_f32_fp8((int)b, 0);
}

// ---------- k1: per-block bucket histogram (LDS only, zero global atomics) ----------
__global__ __launch_bounds__(256) void bucket_hist(const int* __restrict__ dst, int E, int N,
                                                   int* __restrict__ histo) {
  __shared__ int h[8];
  int t = threadIdx.x, b = blockIdx.x;
  if (t < 8) h[t] = 0;
  __syncthreads();
  int per = (N + 7) >> 3;
  int e0 = (int)((long long)b * E / NB);
  int e1 = (int)((long long)(b + 1) * E / NB);
  for (int e = e0 + t; e < e1; e += 256) atomicAdd(&h[dst[e] / per], 1);
  __syncthreads();
  if (t < 8) histo[t * NB + b] = h[t];  // bucket-major
}

// ---------- k2: exclusive scan of 8192 counts (single block) ----------
__device__ __forceinline__ int wave_incl_scan(int v, int lane) {
#pragma unroll
  for (int off = 1; off < 64; off <<= 1) {
    int u = __shfl_up(v, off, 64);
    if (lane >= off) v += u;
  }
  return v;
}

__global__ __launch_bounds__(1024) void scan_offs(const int* __restrict__ histo,
                                                  int* __restrict__ offs) {
  __shared__ int wsums[16];
  __shared__ int carry_s;
  int t = threadIdx.x, lane = t & 63, wv = t >> 6;
  if (t == 0) carry_s = 0;
  __syncthreads();
  for (int seg = 0; seg < 8; ++seg) {
    int v = histo[seg * 1024 + t];
    int iv = wave_incl_scan(v, lane);
    if (lane == 63) wsums[wv] = iv;
    __syncthreads();
    int wbase = 0;
#pragma unroll
    for (int w = 0; w < 16; ++w) wbase += (w < wv) ? wsums[w] : 0;
    int incl = wbase + iv;
    int carry = carry_s;
    __syncthreads();
    offs[seg * 1024 + t] = carry + incl - v;
    if (t == 1023) carry_s = carry + incl;
    __syncthreads();
  }
}

// ---------- k3: scatter edges to bucket-major ebuf (LDS cursors, deterministic) ----------
__global__ __launch_bounds__(256) void bucket_scatter(const int* __restrict__ src,
                                                      const int* __restrict__ dst, int E, int N,
                                                      const int* __restrict__ offs,
                                                      int2* __restrict__ ebuf) {
  __shared__ int cur[8];
  int t = threadIdx.x, b = blockIdx.x;
  if (t < 8) cur[t] = offs[t * NB + b];
  __syncthreads();
  int per = (N + 7) >> 3;
  int e0 = (int)((long long)b * E / NB);
  int e1 = (int)((long long)(b + 1) * E / NB);
  for (int e = e0 + t; e < e1; e += 256) {
    int d = dst[e];
    int s = src[e];
    int pos = atomicAdd(&cur[d / per], 1);
    ebuf[pos] = make_int2(d, s);
  }
}

// ---------- k4: fill padded CSR; XCD-local bucket, 8 sub-windows (~400KB hot) ----------
__global__ __launch_bounds__(256) void fill_sub(const int2* __restrict__ ebuf,
                                                const int* __restrict__ offs, int E, int N,
                                                int* __restrict__ deg,
                                                int* __restrict__ colpad) {
  int k = blockIdx.x & 7;          // XCD / bucket
  int rest = blockIdx.x >> 3;
  int sub = rest & 7;              // sub-window
  int chunk = rest >> 3;           // 0..31
  int e0k = offs[k * 1024];
  int e1k = (k == 7) ? E : offs[(k + 1) * 1024];
  int n = e1k - e0k;
  int i0 = e0k + (int)((long long)chunk * n / 32);
  int i1 = e0k + (int)((long long)(chunk + 1) * n / 32);
  int per = (N + 7) >> 3;
  int sper = (per + 7) >> 3;
  int lo = k * per + sub * sper;
  int hi = min(min(N, (k + 1) * per), lo + sper);
  for (int i = i0 + (int)threadIdx.x; i < i1; i += 256) {
    int2 p = ebuf[i];
    if (p.x >= lo && p.x < hi) {
      int pos = atomicAdd(&deg[p.x], 1);
      if (pos < SLOTS) colpad[(size_t)p.x * SLOTS + pos] = p.y;
    }
  }
}

__global__ __launch_bounds__(256) void calc_dinv(const int* __restrict__ deg,
                                                 float* __restrict__ dinv, int N) {
  int i = blockIdx.x * 256 + threadIdx.x;
  if (i < N) dinv[i] = rsqrtf((float)(deg[i] + 1));  // +1 self loop
}

// ---------- GEMM: gbuf[i][c] = fp8(dinv[i] * sum_k in[i][k]*W[k][c]) ----------
template <int K, typename Tin>
__global__ __launch_bounds__(256) void gemm_dinv(const Tin* __restrict__ in,
                                                 const float* __restrict__ W,
                                                 const float* __restrict__ dinv,
                                                 unsigned char* __restrict__ out, int N, int tiles) {
  constexpr int K4 = K / 4;
  __shared__ float4 Ws4[64][K4];
  __shared__ float Xs[32][K];
  int t = threadIdx.x;
  for (int j = t; j < 64 * K4; j += 256) {
    int c = j / K4, k4 = j % K4;
    float4 v;
    v.x = W[(4 * k4 + 0) * 64 + c];
    v.y = W[(4 * k4 + 1) * 64 + c];
    v.z = W[(4 * k4 + 2) * 64 + c];
    v.w = W[(4 * k4 + 3) * 64 + c];
    Ws4[c][k4 ^ (c & 7)] = v;
  }
  __syncthreads();
  int c0 = t & 31, rg = t >> 5;
  for (int tile = blockIdx.x; tile < tiles; tile += gridDim.x) {
    int row0 = tile * 32;
    if constexpr (sizeof(Tin) == 4) {
      for (int j = t; j < 32 * K4; j += 256) {
        int r = j / K4, k4 = j % K4;
        int rr = row0 + r;
        float4 v = (rr < N) ? *(const float4*)&in[(size_t)rr * K + 4 * k4]
                            : make_float4(0.f, 0.f, 0.f, 0.f);
        *(float4*)&Xs[r][4 * k4] = v;
      }
    } else {
      for (int j = t; j < 32 * (K / 2); j += 256) {
        int r = j / (K / 2), kk = j % (K / 2);
        int rr = row0 + r;
        float2 v = make_float2(0.f, 0.f);
        if (rr < N) {
          __half2 h = *(const __half2*)&in[(size_t)rr * K + 2 * kk];
          v = __half22float2(h);
        }
        Xs[r][2 * kk] = v.x;
        Xs[r][2 * kk + 1] = v.y;
      }
    }
    __syncthreads();
    float acc[4][2];
#pragma unroll
    for (int r = 0; r < 4; ++r) { acc[r][0] = 0.f; acc[r][1] = 0.f; }
#pragma unroll 4
    for (int k4 = 0; k4 < K4; ++k4) {
      float4 w0 = Ws4[c0][k4 ^ (c0 & 7)];
      float4 w1 = Ws4[c0 + 32][k4 ^ (c0 & 7)];
#pragma unroll
      for (int r = 0; r < 4; ++r) {
        float4 xv = *(const float4*)&Xs[rg * 4 + r][4 * k4];
        acc[r][0] = fmaf(xv.w, w0.w, fmaf(xv.z, w0.z, fmaf(xv.y, w0.y, fmaf(xv.x, w0.x, acc[r][0]))));
        acc[r][1] = fmaf(xv.w, w1.w, fmaf(xv.z, w1.z, fmaf(xv.y, w1.y, fmaf(xv.x, w1.x, acc[r][1]))));
      }
    }
#pragma unroll
    for (int r = 0; r < 4; ++r) {
      int row = row0 + rg * 4 + r;
      if (row < N) {
        float s = dinv[row];
        out[(size_t)row * 64 + c0]      = f32_to_fp8(acc[r][0] * s);
        out[(size_t)row * 64 + c0 + 32] = f32_to_fp8(acc[r][1] * s);
      }
    }
    __syncthreads();
  }
}

// ---------- aggregation, 4-edge-parallel ----------
// Wave = 4 groups x 16 lanes. Group q processes edge slots {4i+q}; lane covers
// features 4*sub..4*sub+3 as one uint (4 fp8). One load inst = 4 edges in flight.
// Next node's deg/colpad row prefetched during current gathers.
__global__ __launch_bounds__(256) void aggregate4(const unsigned char* __restrict__ g,
                                                  const int* __restrict__ deg_arr,
                                                  const int* __restrict__ colpad,
                                                  const float* __restrict__ dinv,
                                                  const float* __restrict__ bias,
                                                  const int* __restrict__ batch,
                                                  __half* __restrict__ out,
                                                  float* __restrict__ poolsum,
                                                  float* __restrict__ poolcnt,
                                                  int N, int mode) {
  int lane = threadIdx.x & 63;
  int group = lane >> 4;   // 0..3
  int sub = lane & 15;     // 0..15 -> features 4*sub..4*sub+3
  int wave = blockIdx.x * 4 + (threadIdx.x >> 6);
  int nwaves = gridDim.x * 4;
  int per = (N + nwaves - 1) / nwaves;
  int n0 = wave * per, n1 = min(N, n0 + per);
  if (n0 >= n1) return;
  float4 b4 = ((const float4*)bias)[sub];
  int cur = mode ? batch[n0] : 0;
  float p0 = 0.f, p1 = 0.f, p2 = 0.f, p3 = 0.f, pcnt = 0.f;

  int degc = min(deg_arr[n0], SLOTS);
  int nbc = colpad[(size_t)n0 * SLOTS + lane];

  for (int node = n0; node < n1; ++node) {
    // prefetch next node's metadata (consumed next iteration)
    int degn = 0, nbn = 0;
    if (node + 1 < n1) {
      degn = deg_arr[node + 1];
      nbn = colpad[(size_t)(node + 1) * SLOTS + lane];
    }
    // self row (dinv-prescaled); all lanes load (groups alias same 64B line),
    // only group 0 accumulates it.
    unsigned int su = *(const unsigned int*)(g + (size_t)node * 64 + 4 * sub);
    float a0, a1, a2, a3;
    if (group == 0) {
      a0 = __builtin_amdgcn_cvt_f32_fp8(su, 0);
      a1 = __builtin_amdgcn_cvt_f32_fp8(su, 1);
      a2 = __builtin_amdgcn_cvt_f32_fp8(su, 2);
      a3 = __builtin_amdgcn_cvt_f32_fp8(su, 3);
    } else {
      a0 = a1 = a2 = a3 = 0.f;
    }
    int fs = degc >> 2;      // full 4-edge steps
    int rem = degc & 3;
#pragma unroll 4
    for (int i = 0; i < fs; ++i) {
      int s = __shfl(nbc, 4 * i + group, 64);  // per-lane src: 4 edges at once
      unsigned int u = *(const unsigned int*)(g + (size_t)s * 64 + 4 * sub);
      a0 += __builtin_amdgcn_cvt_f32_fp8(u, 0);
      a1 += __builtin_amdgcn_cvt_f32_fp8(u, 1);
      a2 += __builtin_amdgcn_cvt_f32_fp8(u, 2);
      a3 += __builtin_amdgcn_cvt_f32_fp8(u, 3);
    }
    if (rem) {
      int idx = 4 * fs + group;
      int s = __shfl(nbc, min(idx, 63), 64);
      bool v = group < rem;
      int sa = v ? s : 0;
      unsigned int u = *(const unsigned int*)(g + (size_t)sa * 64 + 4 * sub);
      if (v) {
        a0 += __builtin_amdgcn_cvt_f32_fp8(u, 0);
        a1 += __builtin_amdgcn_cvt_f32_fp8(u, 1);
        a2 += __builtin_amdgcn_cvt_f32_fp8(u, 2);
        a3 += __builtin_amdgcn_cvt_f32_fp8(u, 3);
      }
    }
    // cross-group reduction (features identical across groups)
    a0 += __shfl_xor(a0, 16, 64); a0 += __shfl_xor(a0, 32, 64);
    a1 += __shfl_xor(a1, 16, 64); a1 += __shfl_xor(a1, 32, 64);
    a2 += __shfl_xor(a2, 16, 64); a2 += __shfl_xor(a2, 32, 64);
    a3 += __shfl_xor(a3, 16, 64); a3 += __shfl_xor(a3, 32, 64);

    float sc = dinv[node];
    float r0 = fmaf(sc, a0, b4.x);
    float r1 = fmaf(sc, a1, b4.y);
    float r2 = fmaf(sc, a2, b4.z);
    float r3 = fmaf(sc, a3, b4.w);
    if (mode == 0) {
      if (group == 0) {
        __half2 h01 = __floats2half2_rn(fmaxf(r0, 0.f), fmaxf(r1, 0.f));
        __half2 h23 = __floats2half2_rn(fmaxf(r2, 0.f), fmaxf(r3, 0.f));
        __half2* dst = (__half2*)(out + (size_t)node * 64 + 4 * sub);
        dst[0] = h01;
        dst[1] = h23;
      }
    } else {
      int bg = batch[node];
      if (bg != cur) {
        if (group == 0) {
          atomicAdd(&poolsum[cur * 64 + 4 * sub + 0], p0);
          atomicAdd(&poolsum[cur * 64 + 4 * sub + 1], p1);
          atomicAdd(&poolsum[cur * 64 + 4 * sub + 2], p2);
          atomicAdd(&poolsum[cur * 64 + 4 * sub + 3], p3);
          if (lane == 0) atomicAdd(&poolcnt[cur], pcnt);
        }
        p0 = p1 = p2 = p3 = 0.f; pcnt = 0.f; cur = bg;
      }
      p0 += r0; p1 += r1; p2 += r2; p3 += r3; pcnt += 1.f;
    }
    degc = min(degn, SLOTS);
    nbc = nbn;
  }
  if (mode && group == 0) {
    atomicAdd(&poolsum[cur * 64 + 4 * sub + 0], p0);
    atomicAdd(&poolsum[cur * 64 + 4 * sub + 1], p1);
    atomicAdd(&poolsum[cur * 64 + 4 * sub + 2], p2);
    atomicAdd(&poolsum[cur * 64 + 4 * sub + 3], p3);
    if (lane == 0) atomicAdd(&poolcnt[cur], pcnt);
  }
}

__global__ __launch_bounds__(256) void finalize(const float* __restrict__ poolsum,
                                                const float* __restrict__ poolcnt,
                                                float* __restrict__ out, int Gn) {
  int i = blockIdx.x * 256 + threadIdx.x;
  if (i < Gn * 64) {
    float c = poolcnt[i >> 6];
    out[i] = poolsum[i] / fmaxf(c, 1.f);
  }
}

extern "C" void kernel_launch(void* const* d_in, const int* in_sizes, int n_in,
                              void* d_out, int out_size, void* d_ws, size_t ws_size,
                              hipStream_t stream) {
  const float* x   = (const float*)d_in[0];
  const int* ei    = (const int*)d_in[1];
  const int* batch = (const int*)d_in[2];
  const float* W1  = (const float*)d_in[3];
  const float* b1  = (const float*)d_in[4];
  const float* W2  = (const float*)d_in[5];
  const float* b2  = (const float*)d_in[6];
  float* out = (float*)d_out;

  int N  = in_sizes[2];
  int E  = in_sizes[1] / 2;
  int Gn = out_size / 64;

  char* ws = (char*)d_ws;
  size_t off = 0;
  auto alloc = [&](size_t bytes) -> void* {
    void* p = ws + off;
    off = (off + bytes + 255) & ~(size_t)255;
    return p;
  };
  int* deg       = (int*)alloc(4ull * N);
  float* poolsum = (float*)alloc(4ull * Gn * 64);
  float* poolcnt = (float*)alloc(4ull * Gn);
  size_t zero_bytes = off;  // zero-init region
  int* histo     = (int*)alloc(4ull * 8 * NB);
  int* offs      = (int*)alloc(4ull * 8 * NB);
  int2* ebuf     = (int2*)alloc(8ull * E);
  int* colpad    = (int*)alloc(4ull * (size_t)N * SLOTS);
  float* dinv    = (float*)alloc(4ull * N);
  unsigned char* gbuf = (unsigned char*)alloc(1ull * (size_t)N * 64);
  __half* ybuf   = (__half*)alloc(2ull * (size_t)N * 64);
  (void)ws_size; (void)n_in;

  hipMemsetAsync(d_ws, 0, zero_bytes, stream);

  const int* srcv = ei;
  const int* dstv = ei + E;
  int tiles = (N + 31) / 32;

  // CSR build: histogram -> scan -> deterministic scatter -> L2-local sub-window fill
  bucket_hist<<<NB, 256, 0, stream>>>(dstv, E, N, histo);
  scan_offs<<<1, 1024, 0, stream>>>(histo, offs);
  bucket_scatter<<<NB, 256, 0, stream>>>(srcv, dstv, E, N, offs, ebuf);
  fill_sub<<<8 * 8 * 32, 256, 0, stream>>>(ebuf, offs, E, N, deg, colpad);
  calc_dinv<<<(N + 255) / 256, 256, 0, stream>>>(deg, dinv, N);

  // layer 1
  gemm_dinv<128, float><<<1536, 256, 0, stream>>>(x, W1, dinv, gbuf, N, tiles);
  aggregate4<<<2048, 256, 0, stream>>>(gbuf, deg, colpad, dinv, b1, batch, ybuf,
                                       nullptr, nullptr, N, 0);
  // layer 2 (+fused mean-pool partials)
  gemm_dinv<64, __half><<<1536, 256, 0, stream>>>(ybuf, W2, dinv, gbuf, N, tiles);
  aggregate4<<<2048, 256, 0, stream>>>(gbuf, deg, colpad, dinv, b2, batch, nullptr,
                                       poolsum, poolcnt, N, 1);
  finalize<<<(Gn * 64 + 255) / 256, 256, 0, stream>>>(poolsum, poolcnt, out, Gn);
}